// Round 2
// baseline (794.821 us; speedup 1.0000x reference)
//
#include <hip/hip_runtime.h>
#include <math.h>

#define MIN_NORM 1e-15f

// B=32, S=256, V=30000, L=1024, H=4, D=64

__device__ __forceinline__ float wred(float v){
#pragma unroll
  for(int o=32;o;o>>=1) v += __shfl_xor(v, o, 64);
  return v;
}

// ---- kernel 1: ux[b,s,h,:] = mobius_matvec(U, word_embed[x[b,s]]), uxn2 = ||ux||^2 ----
__global__ __launch_bounds__(64) void k_ux(const int* __restrict__ x,
    const float* __restrict__ wemb, const float* __restrict__ U,
    float* __restrict__ ux, float* __restrict__ uxn2){
  const int bid = blockIdx.x;          // (b*S+s)*4 + h
  const int h = bid & 3;
  const int bs = bid >> 2;
  const int lane = threadIdx.x;
  const int v = x[bs];
  float xi = wemb[(size_t)v*256 + h*64 + lane];
  __shared__ __align__(16) float xs[64];
  xs[lane] = xi;
  __syncthreads();
  float nx2 = wred(xi*xi);
  const float* Urow = U + h*4096 + lane*64;
  float a0=0.f,a1=0.f,a2=0.f,a3=0.f;
#pragma unroll
  for(int j=0;j<64;j+=4){
    float4 u4 = *(const float4*)(Urow + j);
    float4 x4 = *(const float4*)(xs + j);
    a0 = fmaf(u4.x, x4.x, a0);
    a1 = fmaf(u4.y, x4.y, a1);
    a2 = fmaf(u4.z, x4.z, a2);
    a3 = fmaf(u4.w, x4.w, a3);
  }
  float mx = (a0+a1)+(a2+a3);
  float nmx2 = wred(mx*mx);
  float xn  = fmaxf(sqrtf(nx2),  MIN_NORM);
  float mxn = fmaxf(sqrtf(nmx2), MIN_NORM);
  float scale = tanhf(mxn/xn * atanhf(fminf(xn, 1.f-1e-7f)));
  ux[(size_t)bid*64 + lane] = scale * mx / mxn;   // mx==0 -> 0 naturally
  if(lane==0) uxn2[bid] = (nmx2 > 0.f) ? scale*scale : 0.f;
}

// ---- kernel 2: sequential Mobius RNN, one wave per (b,h) chain ----
__global__ __launch_bounds__(64) void k_rnn(const float* __restrict__ W,
    const float* __restrict__ bvec, const float* __restrict__ ux,
    const float* __restrict__ uxn2, float* __restrict__ enc){
  const int b = blockIdx.x >> 2, h = blockIdx.x & 3;
  const int lane = threadIdx.x;
  // W row i (=lane) in registers
  float wrow[64];
  const float* Wp = W + h*4096 + lane*64;
#pragma unroll
  for(int j=0;j<64;j+=4){
    float4 w4 = *(const float4*)(Wp + j);
    wrow[j]=w4.x; wrow[j+1]=w4.y; wrow[j+2]=w4.z; wrow[j+3]=w4.w;
  }
  const float bi = bvec[h*64 + lane];
  const float bn2 = wred(bi*bi);
  __shared__ __align__(16) float hs[64];
  hs[lane] = 0.f;
  float hreg = 0.f;
  __syncthreads();
  const float* uxp   = ux   + (size_t)b*65536 + h*64;   // + s*256 + lane
  const float* uxn2p = uxn2 + (size_t)b*1024  + h;      // + s*4
  float* encp        = enc  + (size_t)b*65536 + h*64;
  float ux_next  = uxp[lane];
  float uy2_next = uxn2p[0];
  for(int s=0;s<256;s++){
    const float uxi = ux_next, uy2 = uy2_next;
    if(s < 255){
      ux_next  = uxp[(size_t)(s+1)*256 + lane];   // prefetch overlaps matvec
      uy2_next = uxn2p[(s+1)*4];
    }
    // phase A: mx = W h ; reduce ||mx||^2 and ||h||^2 together
    float a0=0.f,a1=0.f,a2=0.f,a3=0.f;
#pragma unroll
    for(int j=0;j<64;j+=4){
      float4 h4 = *(const float4*)(hs + j);
      a0 = fmaf(wrow[j],   h4.x, a0);
      a1 = fmaf(wrow[j+1], h4.y, a1);
      a2 = fmaf(wrow[j+2], h4.z, a2);
      a3 = fmaf(wrow[j+3], h4.w, a3);
    }
    float mx = (a0+a1)+(a2+a3);
    float nmx2 = wred(mx*mx);
    float nh2  = wred(hreg*hreg);
    float xn  = fmaxf(sqrtf(nh2),  MIN_NORM);
    float mxn = fmaxf(sqrtf(nmx2), MIN_NORM);
    float scale = tanhf(mxn/xn * atanhf(fminf(xn, 1.f-1e-7f)));
    float wh  = scale * mx / mxn;
    float wx2 = (nmx2 > 0.f) ? scale*scale : 0.f;   // ||wh||^2
    // phase B: z1 = mobius_add(wh, ux)
    float xy = wred(wh*uxi);
    float A  = 1.f + 2.f*xy + uy2;
    float Bc = 1.f - wx2;
    float den = fmaxf(1.f + 2.f*xy + wx2*uy2, MIN_NORM);
    float z1 = (A*wh + Bc*uxi)/den;
    // phase C: h_new = mobius_add(z1, b) ; reduce z1.b and ||z1||^2 together
    float zb = wred(z1*bi);
    float zz = wred(z1*z1);
    float A2 = 1.f + 2.f*zb + bn2;
    float B2 = 1.f - zz;
    float den2 = fmaxf(1.f + 2.f*zb + zz*bn2, MIN_NORM);
    float hn = (A2*z1 + B2*bi)/den2;
    encp[(size_t)s*256 + lane] = hn;
    hreg = hn;
    __syncthreads();
    hs[lane] = hn;
    __syncthreads();
  }
}

// ---- row squared-norms: src is [nrows][64] ----
__global__ __launch_bounds__(256) void k_norm2(const float* __restrict__ src,
    float* __restrict__ dst, int nrows){
  const int row = blockIdx.x*4 + (threadIdx.x>>6);
  const int lane = threadIdx.x & 63;
  if(row >= nrows) return;
  float v = src[(size_t)row*64 + lane];
  float n2 = wred(v*v);
  if(lane==0) dst[row] = n2;
}

__device__ __forceinline__ float pdist(float dot, float a, float lb){
  float c2  = fmaxf(a + lb - 2.f*dot, 0.f);
  float den = fmaxf((1.f-a)*(1.f-lb), MIN_NORM);
  float arg = fmaxf(1.f + 2.f*c2/den, 1.f + 1e-7f);
  return acoshf(arg);
}

// ---- kernel 3: interaction[b,l,s] = sum_h poinc_dist(enc[b,s,h],lab[l,h]) ----
#define LP 68  // padded LDS stride (64 + 4), keeps b128 16B-aligned, kills conflicts
__global__ __launch_bounds__(256) void k_dist(const float* __restrict__ enc,
    const float* __restrict__ lab, const float* __restrict__ an,
    const float* __restrict__ lbn, float* __restrict__ inter){
  __shared__ __align__(16) float eT[4*16*LP];
  __shared__ __align__(16) float lT[4*16*LP];
  const int bs0 = blockIdx.x*64, l0 = blockIdx.y*64;
  const int t = threadIdx.x;
  const int tr = t>>4, tc = t&15;
  const int ldr = t>>2, ldp = t&3;
  float acc[4][4][4];
#pragma unroll
  for(int h=0;h<4;h++)
#pragma unroll
    for(int i=0;i<4;i++)
#pragma unroll
      for(int j=0;j<4;j++) acc[h][i][j]=0.f;

  for(int c=0;c<4;c++){
    if(c) __syncthreads();
#pragma unroll
    for(int h=0;h<4;h++){
      float4 ev = *(const float4*)&enc[(size_t)(bs0+ldr)*256 + h*64 + c*16 + ldp*4];
      float4 lv = *(const float4*)&lab[(size_t)(l0 +ldr)*256 + h*64 + c*16 + ldp*4];
      int base = (h*16 + ldp*4)*LP + ldr;
      eT[base     ] = ev.x; eT[base+  LP] = ev.y; eT[base+2*LP] = ev.z; eT[base+3*LP] = ev.w;
      lT[base     ] = lv.x; lT[base+  LP] = lv.y; lT[base+2*LP] = lv.z; lT[base+3*LP] = lv.w;
    }
    __syncthreads();
#pragma unroll
    for(int dd=0;dd<16;dd++){
#pragma unroll
      for(int h=0;h<4;h++){
        float4 e4 = *(const float4*)&eT[(h*16+dd)*LP + tr*4];
        float4 l4 = *(const float4*)&lT[(h*16+dd)*LP + tc*4];
        float ee[4] = {e4.x,e4.y,e4.z,e4.w};
        float ll[4] = {l4.x,l4.y,l4.z,l4.w};
#pragma unroll
        for(int i=0;i<4;i++)
#pragma unroll
          for(int j=0;j<4;j++)
            acc[h][i][j] = fmaf(ee[i], ll[j], acc[h][i][j]);
      }
    }
  }
  const int b = bs0 >> 8;
#pragma unroll
  for(int i=0;i<4;i++){
    const int bs = bs0 + tr*4 + i;
    const int s  = bs & 255;
    float4 ah = *(const float4*)&an[(size_t)bs*4];
#pragma unroll
    for(int j=0;j<4;j++){
      const int l = l0 + tc*4 + j;
      float4 lb = *(const float4*)&lbn[(size_t)l*4];
      float d = pdist(acc[0][i][j], ah.x, lb.x)
              + pdist(acc[1][i][j], ah.y, lb.y)
              + pdist(acc[2][i][j], ah.z, lb.z)
              + pdist(acc[3][i][j], ah.w, lb.w);
      inter[((size_t)b*1024 + l)*256 + s] = d;
    }
  }
}

// ---- kernel 4: out[b,l] = w2 . relu(w1 @ inter[b,l,:] + b1) + b2 ----
__global__ __launch_bounds__(256) void k_mlp(const float* __restrict__ inter,
    const float* __restrict__ w1, const float* __restrict__ b1,
    const float* __restrict__ w2, const float* __restrict__ b2,
    float* __restrict__ out){
  __shared__ __align__(16) float rows[32*256];
  __shared__ float part[4][16];
  const int b  = blockIdx.x >> 5;
  const int l0 = (blockIdx.x & 31)*32;
  const int t = threadIdx.x;
  const float* ip = inter + ((size_t)b*1024 + l0)*256;
#pragma unroll
  for(int k=0;k<8;k++){
    int idx = k*1024 + t*4;
    *(float4*)&rows[idx] = *(const float4*)&ip[idx];
  }
  __syncthreads();
  const int f = t & 127, g = t >> 7;
  float acc[16];
#pragma unroll
  for(int li=0;li<16;li++) acc[li]=0.f;
  const float* wp = w1 + (size_t)f*256;
  for(int s=0;s<256;s+=4){
    float4 w4 = *(const float4*)&wp[s];
#pragma unroll
    for(int li=0;li<16;li++){
      float4 r4 = *(const float4*)&rows[(g*16+li)*256 + s];
      acc[li] = fmaf(r4.w, w4.w, fmaf(r4.z, w4.z, fmaf(r4.y, w4.y, fmaf(r4.x, w4.x, acc[li]))));
    }
  }
  const float bb1 = b1[f], ww2 = w2[f];
  const int wave = t>>6, lane = t&63;
#pragma unroll
  for(int li=0;li<16;li++){
    float vv = fmaxf(acc[li] + bb1, 0.f) * ww2;
    vv = wred(vv);
    if(lane==0) part[wave][li] = vv;
  }
  __syncthreads();
  if(t < 32){
    int g2 = t>>4, li = t&15;
    out[(size_t)b*1024 + l0 + g2*16 + li] = part[2*g2][li] + part[2*g2+1][li] + b2[0];
  }
}

extern "C" void kernel_launch(void* const* d_in, const int* in_sizes, int n_in,
                              void* d_out, int out_size, void* d_ws, size_t ws_size,
                              hipStream_t stream){
  const int*   x    = (const int*)d_in[0];
  const float* wemb = (const float*)d_in[1];
  const float* lab  = (const float*)d_in[2];
  const float* W    = (const float*)d_in[3];
  const float* U    = (const float*)d_in[4];
  const float* bv   = (const float*)d_in[5];
  const float* w1   = (const float*)d_in[6];
  const float* b1   = (const float*)d_in[7];
  const float* w2   = (const float*)d_in[8];
  const float* b2   = (const float*)d_in[9];
  float* out = (float*)d_out;

  float* ws    = (float*)d_ws;
  float* enc   = ws;                      // 2,097,152 f  [B*S*H][64]
  float* an    = enc + 2097152;           //    32,768 f  [B*S*H]
  float* lbn   = an  + 32768;             //     4,096 f  [L*H]
  float* ux    = lbn + 4096;              // 2,097,152 f  (dead after k_rnn)
  float* uxn2  = ux  + 2097152;           //    32,768 f  (dead after k_rnn)
  float* inter = lbn + 4096;              // 8,388,608 f  [B][L][S] (overlaps ux/uxn2)
  // peak ws use: 2134016 + 8388608 floats = ~40.1 MB

  k_ux   <<<32768, 64, 0, stream>>>(x, wemb, U, ux, uxn2);
  k_norm2<<<1024, 256, 0, stream>>>(lab, lbn, 4096);
  k_rnn  <<<128,   64, 0, stream>>>(W, bv, ux, uxn2, enc);
  k_norm2<<<8192, 256, 0, stream>>>(enc, an, 32768);
  dim3 g3(128, 16);
  k_dist <<<g3,   256, 0, stream>>>(enc, lab, an, lbn, inter);
  k_mlp  <<<1024, 256, 0, stream>>>(inter, w1, b1, w2, b2, out);
}

// Round 3
// 623.040 us; speedup vs baseline: 1.2757x; 1.2757x over previous
//
#include <hip/hip_runtime.h>
#include <math.h>

#define MIN_NORM 1e-15f

// B=32, S=256, V=30000, L=1024, H=4, D=64

// ---- fast scalar helpers ----
__device__ __forceinline__ float frcp(float x){ return __builtin_amdgcn_rcpf(x); }
__device__ __forceinline__ float fsqrt(float x){ return __builtin_amdgcn_sqrtf(x); }
__device__ __forceinline__ float fast_atanh(float x){        // x in [0, 1-1e-7]
  return 0.5f * __logf((1.f + x) * frcp(1.f - x));
}
__device__ __forceinline__ float fast_tanh(float y){         // y >= 0
  float e = __expf(-2.f * y);
  return (1.f - e) * frcp(1.f + e);
}

// ---- DPP wave64 sum reductions (result broadcast via readlane 63) ----
#define DPPADD(v, ctrl) \
  v += __int_as_float(__builtin_amdgcn_update_dpp(0, __float_as_int(v), ctrl, 0xf, 0xf, false));

__device__ __forceinline__ float wred_b(float v){
  DPPADD(v,0x111) DPPADD(v,0x112) DPPADD(v,0x114) DPPADD(v,0x118)
  DPPADD(v,0x142) DPPADD(v,0x143)
  return __int_as_float(__builtin_amdgcn_readlane(__float_as_int(v), 63));
}
__device__ __forceinline__ void wred4_b(float& v0, float& v1, float& v2, float& v3){
  DPPADD(v0,0x111) DPPADD(v1,0x111) DPPADD(v2,0x111) DPPADD(v3,0x111)
  DPPADD(v0,0x112) DPPADD(v1,0x112) DPPADD(v2,0x112) DPPADD(v3,0x112)
  DPPADD(v0,0x114) DPPADD(v1,0x114) DPPADD(v2,0x114) DPPADD(v3,0x114)
  DPPADD(v0,0x118) DPPADD(v1,0x118) DPPADD(v2,0x118) DPPADD(v3,0x118)
  DPPADD(v0,0x142) DPPADD(v1,0x142) DPPADD(v2,0x142) DPPADD(v3,0x142)
  DPPADD(v0,0x143) DPPADD(v1,0x143) DPPADD(v2,0x143) DPPADD(v3,0x143)
  v0 = __int_as_float(__builtin_amdgcn_readlane(__float_as_int(v0), 63));
  v1 = __int_as_float(__builtin_amdgcn_readlane(__float_as_int(v1), 63));
  v2 = __int_as_float(__builtin_amdgcn_readlane(__float_as_int(v2), 63));
  v3 = __int_as_float(__builtin_amdgcn_readlane(__float_as_int(v3), 63));
}

__device__ __forceinline__ float wred(float v){   // shfl version (TLP-rich kernels)
#pragma unroll
  for(int o=32;o;o>>=1) v += __shfl_xor(v, o, 64);
  return v;
}

#define LDS_FENCE() asm volatile("s_waitcnt lgkmcnt(0)" ::: "memory")

// ---- kernel 1: ux = mobius_matvec(U, wemb[x]); also uxn2=||ux||^2, uxb=ux.b ----
__global__ __launch_bounds__(256) void k_ux(const int* __restrict__ x,
    const float* __restrict__ wemb, const float* __restrict__ U,
    const float* __restrict__ bvec,
    float* __restrict__ ux, float* __restrict__ uxn2, float* __restrict__ uxb){
  __shared__ __align__(16) float xs[4][64];
  const int wv = threadIdx.x >> 6, lane = threadIdx.x & 63;
  const int bid = blockIdx.x*4 + wv;   // (b*S+s)*4 + h
  const int h = bid & 3;
  const int bs = bid >> 2;
  const int v = x[bs];
  float xi = wemb[(size_t)v*256 + h*64 + lane];
  const float bi = bvec[h*64 + lane];
  xs[wv][lane] = xi;
  LDS_FENCE();
  const float* Urow = U + h*4096 + lane*64;
  float a0=0.f,a1=0.f,a2=0.f,a3=0.f,a4=0.f,a5=0.f,a6=0.f,a7=0.f;
#pragma unroll
  for(int j=0;j<64;j+=8){
    float4 u4 = *(const float4*)(Urow + j);
    float4 x4 = *(const float4*)(&xs[wv][j]);
    float4 u5 = *(const float4*)(Urow + j + 4);
    float4 x5 = *(const float4*)(&xs[wv][j+4]);
    a0 = fmaf(u4.x, x4.x, a0); a1 = fmaf(u4.y, x4.y, a1);
    a2 = fmaf(u4.z, x4.z, a2); a3 = fmaf(u4.w, x4.w, a3);
    a4 = fmaf(u5.x, x5.x, a4); a5 = fmaf(u5.y, x5.y, a5);
    a6 = fmaf(u5.z, x5.z, a6); a7 = fmaf(u5.w, x5.w, a7);
  }
  float mx = ((a0+a1)+(a2+a3)) + ((a4+a5)+(a6+a7));
  float t0 = xi*xi, t1 = mx*mx, t2 = mx*bi, t3 = 0.f;
  wred4_b(t0, t1, t2, t3);     // t0=||x||^2, t1=||mx||^2, t2=mx.b
  float xn  = fmaxf(fsqrt(t0), MIN_NORM);
  float mxn = fmaxf(fsqrt(t1), MIN_NORM);
  float scale = fast_tanh(mxn*frcp(xn) * fast_atanh(fminf(xn, 1.f-1e-7f)));
  float sm = scale * frcp(mxn);
  ux[(size_t)bid*64 + lane] = sm * mx;    // mx==0 -> 0
  if(lane==0){
    uxn2[bid] = (t1 > 0.f) ? scale*scale : 0.f;
    uxb[bid]  = sm * t2;
  }
}

// ---- kernel 2: sequential Mobius RNN, one wave per (b,h) chain ----
// Single reduction phase per step: (mx.mx, mx.ux, mx.b, h.h) in one DPP tree.
// All mobius_add norms/dots derived analytically from scalars.
__global__ __launch_bounds__(64) void k_rnn(const float* __restrict__ W,
    const float* __restrict__ bvec, const float* __restrict__ ux,
    const float* __restrict__ uxn2, const float* __restrict__ uxb,
    float* __restrict__ enc){
  const int b = blockIdx.x >> 2, h = blockIdx.x & 3;
  const int lane = threadIdx.x;
  float wrow[64];
  const float* Wp = W + h*4096 + lane*64;
#pragma unroll
  for(int j=0;j<64;j+=4){
    float4 w4 = *(const float4*)(Wp + j);
    wrow[j]=w4.x; wrow[j+1]=w4.y; wrow[j+2]=w4.z; wrow[j+3]=w4.w;
  }
  const float bi = bvec[h*64 + lane];
  const float bn2 = wred_b(bi*bi);
  __shared__ __align__(16) float hs[64];
  hs[lane] = 0.f;
  float hreg = 0.f;
  LDS_FENCE();
  const float* uxp   = ux   + (size_t)b*65536 + h*64;   // + s*256 + lane
  const float* uxn2p = uxn2 + (size_t)b*1024  + h;      // + s*4
  const float* uxbp  = uxb  + (size_t)b*1024  + h;
  float* encp        = enc  + (size_t)b*65536 + h*64;
  float ux_next  = uxp[lane];
  float uy2_next = uxn2p[0];
  float uxb_next = uxbp[0];
  for(int s=0;s<256;s++){
    const float uxi = ux_next, uy2 = uy2_next, uxbv = uxb_next;
    if(s < 255){
      ux_next  = uxp[(size_t)(s+1)*256 + lane];   // prefetch overlaps compute
      uy2_next = uxn2p[(s+1)*4];
      uxb_next = uxbp[(s+1)*4];
    }
    // matvec mx = W h  (hs broadcast reads)
    float a0=0.f,a1=0.f,a2=0.f,a3=0.f,a4=0.f,a5=0.f,a6=0.f,a7=0.f;
#pragma unroll
    for(int j=0;j<64;j+=8){
      float4 h4 = *(const float4*)(hs + j);
      float4 h5 = *(const float4*)(hs + j + 4);
      a0 = fmaf(wrow[j  ], h4.x, a0); a1 = fmaf(wrow[j+1], h4.y, a1);
      a2 = fmaf(wrow[j+2], h4.z, a2); a3 = fmaf(wrow[j+3], h4.w, a3);
      a4 = fmaf(wrow[j+4], h5.x, a4); a5 = fmaf(wrow[j+5], h5.y, a5);
      a6 = fmaf(wrow[j+6], h5.z, a6); a7 = fmaf(wrow[j+7], h5.w, a7);
    }
    float mx = ((a0+a1)+(a2+a3)) + ((a4+a5)+(a6+a7));
    // ONE reduction phase: 4 interleaved DPP trees
    float nmx2 = mx*mx, mxu = mx*uxi, mxb = mx*bi, nh2 = hreg*hreg;
    wred4_b(nmx2, mxu, mxb, nh2);
    // scalar tail (wave-uniform)
    float xn  = fmaxf(fsqrt(nh2),  MIN_NORM);
    float mxn = fmaxf(fsqrt(nmx2), MIN_NORM);
    float at  = fast_atanh(fminf(xn, 1.f-1e-7f));
    float scale = fast_tanh(mxn*frcp(xn) * at);
    float sm  = scale * frcp(mxn);                 // wh = sm*mx
    float wx2 = (nmx2 > 0.f) ? scale*scale : 0.f;  // ||wh||^2
    float xy  = sm * mxu;                          // wh.ux
    // z1 = mobius_add(wh, ux)
    float A   = 1.f + 2.f*xy + uy2;
    float Bc  = 1.f - wx2;
    float iden = frcp(fmaxf(1.f + 2.f*xy + wx2*uy2, MIN_NORM));
    float c1 = A*sm*iden, c2 = Bc*iden;
    float z1 = c1*mx + c2*uxi;                     // per-lane vector
    float zz = (A*A*wx2 + 2.f*A*Bc*xy + Bc*Bc*uy2)*iden*iden;   // ||z1||^2
    float zb = (A*sm*mxb + Bc*uxbv)*iden;                       // z1.b
    // h_new = mobius_add(z1, b)
    float A2 = 1.f + 2.f*zb + bn2;
    float B2 = 1.f - zz;
    float iden2 = frcp(fmaxf(1.f + 2.f*zb + zz*bn2, MIN_NORM));
    float hn = (A2*iden2)*z1 + (B2*iden2)*bi;
    encp[(size_t)s*256 + lane] = hn;               // fire-and-forget
    hreg = hn;
    hs[lane] = hn;
    LDS_FENCE();                                   // order broadcast for next matvec
  }
}

// ---- row squared-norms: src is [nrows][64] ----
__global__ __launch_bounds__(256) void k_norm2(const float* __restrict__ src,
    float* __restrict__ dst, int nrows){
  const int row = blockIdx.x*4 + (threadIdx.x>>6);
  const int lane = threadIdx.x & 63;
  if(row >= nrows) return;
  float v = src[(size_t)row*64 + lane];
  float n2 = wred(v*v);
  if(lane==0) dst[row] = n2;
}

__device__ __forceinline__ float pdist(float dot, float a, float lb){
  float c2  = fmaxf(a + lb - 2.f*dot, 0.f);
  float den = fmaxf((1.f-a)*(1.f-lb), MIN_NORM);
  float arg = fmaxf(1.f + 2.f*c2/den, 1.f + 1e-7f);
  return acoshf(arg);
}

// ---- kernel 3: interaction[b,l,s] = sum_h poinc_dist(enc[b,s,h],lab[l,h]) ----
#define LP 68  // padded LDS stride (64 + 4), keeps b128 16B-aligned, kills conflicts
__global__ __launch_bounds__(256) void k_dist(const float* __restrict__ enc,
    const float* __restrict__ lab, const float* __restrict__ an,
    const float* __restrict__ lbn, float* __restrict__ inter){
  __shared__ __align__(16) float eT[4*16*LP];
  __shared__ __align__(16) float lT[4*16*LP];
  const int bs0 = blockIdx.x*64, l0 = blockIdx.y*64;
  const int t = threadIdx.x;
  const int tr = t>>4, tc = t&15;
  const int ldr = t>>2, ldp = t&3;
  float acc[4][4][4];
#pragma unroll
  for(int h=0;h<4;h++)
#pragma unroll
    for(int i=0;i<4;i++)
#pragma unroll
      for(int j=0;j<4;j++) acc[h][i][j]=0.f;

  for(int c=0;c<4;c++){
    if(c) __syncthreads();
#pragma unroll
    for(int h=0;h<4;h++){
      float4 ev = *(const float4*)&enc[(size_t)(bs0+ldr)*256 + h*64 + c*16 + ldp*4];
      float4 lv = *(const float4*)&lab[(size_t)(l0 +ldr)*256 + h*64 + c*16 + ldp*4];
      int base = (h*16 + ldp*4)*LP + ldr;
      eT[base     ] = ev.x; eT[base+  LP] = ev.y; eT[base+2*LP] = ev.z; eT[base+3*LP] = ev.w;
      lT[base     ] = lv.x; lT[base+  LP] = lv.y; lT[base+2*LP] = lv.z; lT[base+3*LP] = lv.w;
    }
    __syncthreads();
#pragma unroll
    for(int dd=0;dd<16;dd++){
#pragma unroll
      for(int h=0;h<4;h++){
        float4 e4 = *(const float4*)&eT[(h*16+dd)*LP + tr*4];
        float4 l4 = *(const float4*)&lT[(h*16+dd)*LP + tc*4];
        float ee[4] = {e4.x,e4.y,e4.z,e4.w};
        float ll[4] = {l4.x,l4.y,l4.z,l4.w};
#pragma unroll
        for(int i=0;i<4;i++)
#pragma unroll
          for(int j=0;j<4;j++)
            acc[h][i][j] = fmaf(ee[i], ll[j], acc[h][i][j]);
      }
    }
  }
  const int b = bs0 >> 8;
#pragma unroll
  for(int i=0;i<4;i++){
    const int bs = bs0 + tr*4 + i;
    const int s  = bs & 255;
    float4 ah = *(const float4*)&an[(size_t)bs*4];
#pragma unroll
    for(int j=0;j<4;j++){
      const int l = l0 + tc*4 + j;
      float4 lb = *(const float4*)&lbn[(size_t)l*4];
      float d = pdist(acc[0][i][j], ah.x, lb.x)
              + pdist(acc[1][i][j], ah.y, lb.y)
              + pdist(acc[2][i][j], ah.z, lb.z)
              + pdist(acc[3][i][j], ah.w, lb.w);
      inter[((size_t)b*1024 + l)*256 + s] = d;
    }
  }
}

// ---- kernel 4: out[b,l] = w2 . relu(w1 @ inter[b,l,:] + b1) + b2 ----
__global__ __launch_bounds__(256) void k_mlp(const float* __restrict__ inter,
    const float* __restrict__ w1, const float* __restrict__ b1,
    const float* __restrict__ w2, const float* __restrict__ b2,
    float* __restrict__ out){
  __shared__ __align__(16) float rows[32*256];
  __shared__ float part[4][16];
  const int b  = blockIdx.x >> 5;
  const int l0 = (blockIdx.x & 31)*32;
  const int t = threadIdx.x;
  const float* ip = inter + ((size_t)b*1024 + l0)*256;
#pragma unroll
  for(int k=0;k<8;k++){
    int idx = k*1024 + t*4;
    *(float4*)&rows[idx] = *(const float4*)&ip[idx];
  }
  __syncthreads();
  const int f = t & 127, g = t >> 7;
  float acc[16];
#pragma unroll
  for(int li=0;li<16;li++) acc[li]=0.f;
  const float* wp = w1 + (size_t)f*256;
  for(int s=0;s<256;s+=4){
    float4 w4 = *(const float4*)&wp[s];
#pragma unroll
    for(int li=0;li<16;li++){
      float4 r4 = *(const float4*)&rows[(g*16+li)*256 + s];
      acc[li] = fmaf(r4.w, w4.w, fmaf(r4.z, w4.z, fmaf(r4.y, w4.y, fmaf(r4.x, w4.x, acc[li]))));
    }
  }
  const float bb1 = b1[f], ww2 = w2[f];
  const int wave = t>>6, lane = t&63;
#pragma unroll
  for(int li=0;li<16;li++){
    float vv = fmaxf(acc[li] + bb1, 0.f) * ww2;
    vv = wred(vv);
    if(lane==0) part[wave][li] = vv;
  }
  __syncthreads();
  if(t < 32){
    int g2 = t>>4, li = t&15;
    out[(size_t)b*1024 + l0 + g2*16 + li] = part[2*g2][li] + part[2*g2+1][li] + b2[0];
  }
}

extern "C" void kernel_launch(void* const* d_in, const int* in_sizes, int n_in,
                              void* d_out, int out_size, void* d_ws, size_t ws_size,
                              hipStream_t stream){
  const int*   x    = (const int*)d_in[0];
  const float* wemb = (const float*)d_in[1];
  const float* lab  = (const float*)d_in[2];
  const float* W    = (const float*)d_in[3];
  const float* U    = (const float*)d_in[4];
  const float* bv   = (const float*)d_in[5];
  const float* w1   = (const float*)d_in[6];
  const float* b1   = (const float*)d_in[7];
  const float* w2   = (const float*)d_in[8];
  const float* b2   = (const float*)d_in[9];
  float* out = (float*)d_out;

  float* ws    = (float*)d_ws;
  float* enc   = ws;                      // 2,097,152 f  [B*S*H][64]
  float* an    = enc + 2097152;           //    32,768 f  [B*S*H]
  float* lbn   = an  + 32768;             //     4,096 f  [L*H]
  float* ux    = lbn + 4096;              // 2,097,152 f  (dead after k_rnn)
  float* uxn2  = ux  + 2097152;           //    32,768 f
  float* uxb   = uxn2 + 32768;            //    32,768 f
  float* inter = lbn + 4096;              // 8,388,608 f  [B][L][S] (overlaps ux region)
  // peak ws use: 2134016 + 8388608 floats ≈ 42.1 MB

  k_ux   <<<8192, 256, 0, stream>>>(x, wemb, U, bv, ux, uxn2, uxb);
  k_norm2<<<1024, 256, 0, stream>>>(lab, lbn, 4096);
  k_rnn  <<<128,   64, 0, stream>>>(W, bv, ux, uxn2, uxb, enc);
  k_norm2<<<8192, 256, 0, stream>>>(enc, an, 32768);
  dim3 g3(128, 16);
  k_dist <<<g3,   256, 0, stream>>>(enc, lab, an, lbn, inter);
  k_mlp  <<<1024, 256, 0, stream>>>(inter, w1, b1, w2, b2, out);
}

// Round 4
// 492.553 us; speedup vs baseline: 1.6137x; 1.2649x over previous
//
#include <hip/hip_runtime.h>
#include <math.h>

#define MIN_NORM 1e-15f

// B=32, S=256, V=30000, L=1024, H=4, D=64

// ---- fast scalar helpers ----
__device__ __forceinline__ float frcp(float x){ return __builtin_amdgcn_rcpf(x); }
__device__ __forceinline__ float fsqrt(float x){ return __builtin_amdgcn_sqrtf(x); }
__device__ __forceinline__ float fast_atanh(float x){        // x in [0, 1-1e-7]
  return 0.5f * __logf((1.f + x) * frcp(1.f - x));
}
__device__ __forceinline__ float fast_tanh(float y){         // y >= 0
  float e = __expf(-2.f * y);
  return (1.f - e) * frcp(1.f + e);
}

// ---- DPP wave64 sum reductions (result broadcast via readlane 63) ----
#define DPPADD(v, ctrl) \
  v += __int_as_float(__builtin_amdgcn_update_dpp(0, __float_as_int(v), ctrl, 0xf, 0xf, false));

__device__ __forceinline__ float wred_b(float v){
  DPPADD(v,0x111) DPPADD(v,0x112) DPPADD(v,0x114) DPPADD(v,0x118)
  DPPADD(v,0x142) DPPADD(v,0x143)
  return __int_as_float(__builtin_amdgcn_readlane(__float_as_int(v), 63));
}
__device__ __forceinline__ void wred4_b(float& v0, float& v1, float& v2, float& v3){
  DPPADD(v0,0x111) DPPADD(v1,0x111) DPPADD(v2,0x111) DPPADD(v3,0x111)
  DPPADD(v0,0x112) DPPADD(v1,0x112) DPPADD(v2,0x112) DPPADD(v3,0x112)
  DPPADD(v0,0x114) DPPADD(v1,0x114) DPPADD(v2,0x114) DPPADD(v3,0x114)
  DPPADD(v0,0x118) DPPADD(v1,0x118) DPPADD(v2,0x118) DPPADD(v3,0x118)
  DPPADD(v0,0x142) DPPADD(v1,0x142) DPPADD(v2,0x142) DPPADD(v3,0x142)
  DPPADD(v0,0x143) DPPADD(v1,0x143) DPPADD(v2,0x143) DPPADD(v3,0x143)
  v0 = __int_as_float(__builtin_amdgcn_readlane(__float_as_int(v0), 63));
  v1 = __int_as_float(__builtin_amdgcn_readlane(__float_as_int(v1), 63));
  v2 = __int_as_float(__builtin_amdgcn_readlane(__float_as_int(v2), 63));
  v3 = __int_as_float(__builtin_amdgcn_readlane(__float_as_int(v3), 63));
}

__device__ __forceinline__ float wred(float v){   // shfl version (TLP-rich kernels)
#pragma unroll
  for(int o=32;o;o>>=1) v += __shfl_xor(v, o, 64);
  return v;
}

#define LDS_FENCE() asm volatile("s_waitcnt lgkmcnt(0)" ::: "memory")

// ---- kernel 1: ux = mobius_matvec(U, wemb[x]); also uxn2=||ux||^2, uxb=ux.b ----
__global__ __launch_bounds__(256) void k_ux(const int* __restrict__ x,
    const float* __restrict__ wemb, const float* __restrict__ U,
    const float* __restrict__ bvec,
    float* __restrict__ ux, float* __restrict__ uxn2, float* __restrict__ uxb){
  __shared__ __align__(16) float xs[4][64];
  const int wv = threadIdx.x >> 6, lane = threadIdx.x & 63;
  const int bid = blockIdx.x*4 + wv;   // (b*S+s)*4 + h
  const int h = bid & 3;
  const int bs = bid >> 2;
  const int v = x[bs];
  float xi = wemb[(size_t)v*256 + h*64 + lane];
  const float bi = bvec[h*64 + lane];
  xs[wv][lane] = xi;
  LDS_FENCE();
  const float* Urow = U + h*4096 + lane*64;
  float a0=0.f,a1=0.f,a2=0.f,a3=0.f,a4=0.f,a5=0.f,a6=0.f,a7=0.f;
#pragma unroll
  for(int j=0;j<64;j+=8){
    float4 u4 = *(const float4*)(Urow + j);
    float4 x4 = *(const float4*)(&xs[wv][j]);
    float4 u5 = *(const float4*)(Urow + j + 4);
    float4 x5 = *(const float4*)(&xs[wv][j+4]);
    a0 = fmaf(u4.x, x4.x, a0); a1 = fmaf(u4.y, x4.y, a1);
    a2 = fmaf(u4.z, x4.z, a2); a3 = fmaf(u4.w, x4.w, a3);
    a4 = fmaf(u5.x, x5.x, a4); a5 = fmaf(u5.y, x5.y, a5);
    a6 = fmaf(u5.z, x5.z, a6); a7 = fmaf(u5.w, x5.w, a7);
  }
  float mx = ((a0+a1)+(a2+a3)) + ((a4+a5)+(a6+a7));
  float t0 = xi*xi, t1 = mx*mx, t2 = mx*bi, t3 = 0.f;
  wred4_b(t0, t1, t2, t3);     // t0=||x||^2, t1=||mx||^2, t2=mx.b
  float xn  = fmaxf(fsqrt(t0), MIN_NORM);
  float mxn = fmaxf(fsqrt(t1), MIN_NORM);
  float scale = fast_tanh(mxn*frcp(xn) * fast_atanh(fminf(xn, 1.f-1e-7f)));
  float sm = scale * frcp(mxn);
  ux[(size_t)bid*64 + lane] = sm * mx;    // mx==0 -> 0
  if(lane==0){
    uxn2[bid] = (t1 > 0.f) ? scale*scale : 0.f;
    uxb[bid]  = sm * t2;
  }
}

// ---- kernel 2: sequential Mobius RNN, one wave per (b,h) chain ----
// Single reduction phase per step: (mx.mx, mx.ux, mx.b, h.h) in one DPP tree.
// All mobius_add norms/dots derived analytically from scalars.
__global__ __launch_bounds__(64) void k_rnn(const float* __restrict__ W,
    const float* __restrict__ bvec, const float* __restrict__ ux,
    const float* __restrict__ uxn2, const float* __restrict__ uxb,
    float* __restrict__ enc){
  const int b = blockIdx.x >> 2, h = blockIdx.x & 3;
  const int lane = threadIdx.x;
  float wrow[64];
  const float* Wp = W + h*4096 + lane*64;
#pragma unroll
  for(int j=0;j<64;j+=4){
    float4 w4 = *(const float4*)(Wp + j);
    wrow[j]=w4.x; wrow[j+1]=w4.y; wrow[j+2]=w4.z; wrow[j+3]=w4.w;
  }
  const float bi = bvec[h*64 + lane];
  const float bn2 = wred_b(bi*bi);
  __shared__ __align__(16) float hs[64];
  hs[lane] = 0.f;
  float hreg = 0.f;
  LDS_FENCE();
  const float* uxp   = ux   + (size_t)b*65536 + h*64;   // + s*256 + lane
  const float* uxn2p = uxn2 + (size_t)b*1024  + h;      // + s*4
  const float* uxbp  = uxb  + (size_t)b*1024  + h;
  float* encp        = enc  + (size_t)b*65536 + h*64;
  float ux_next  = uxp[lane];
  float uy2_next = uxn2p[0];
  float uxb_next = uxbp[0];
  for(int s=0;s<256;s++){
    const float uxi = ux_next, uy2 = uy2_next, uxbv = uxb_next;
    if(s < 255){
      ux_next  = uxp[(size_t)(s+1)*256 + lane];   // prefetch overlaps compute
      uy2_next = uxn2p[(s+1)*4];
      uxb_next = uxbp[(s+1)*4];
    }
    // matvec mx = W h  (hs broadcast reads)
    float a0=0.f,a1=0.f,a2=0.f,a3=0.f,a4=0.f,a5=0.f,a6=0.f,a7=0.f;
#pragma unroll
    for(int j=0;j<64;j+=8){
      float4 h4 = *(const float4*)(hs + j);
      float4 h5 = *(const float4*)(hs + j + 4);
      a0 = fmaf(wrow[j  ], h4.x, a0); a1 = fmaf(wrow[j+1], h4.y, a1);
      a2 = fmaf(wrow[j+2], h4.z, a2); a3 = fmaf(wrow[j+3], h4.w, a3);
      a4 = fmaf(wrow[j+4], h5.x, a4); a5 = fmaf(wrow[j+5], h5.y, a5);
      a6 = fmaf(wrow[j+6], h5.z, a6); a7 = fmaf(wrow[j+7], h5.w, a7);
    }
    float mx = ((a0+a1)+(a2+a3)) + ((a4+a5)+(a6+a7));
    // ONE reduction phase: 4 interleaved DPP trees
    float nmx2 = mx*mx, mxu = mx*uxi, mxb = mx*bi, nh2 = hreg*hreg;
    wred4_b(nmx2, mxu, mxb, nh2);
    // scalar tail (wave-uniform)
    float xn  = fmaxf(fsqrt(nh2),  MIN_NORM);
    float mxn = fmaxf(fsqrt(nmx2), MIN_NORM);
    float at  = fast_atanh(fminf(xn, 1.f-1e-7f));
    float scale = fast_tanh(mxn*frcp(xn) * at);
    float sm  = scale * frcp(mxn);                 // wh = sm*mx
    float wx2 = (nmx2 > 0.f) ? scale*scale : 0.f;  // ||wh||^2
    float xy  = sm * mxu;                          // wh.ux
    // z1 = mobius_add(wh, ux)
    float A   = 1.f + 2.f*xy + uy2;
    float Bc  = 1.f - wx2;
    float iden = frcp(fmaxf(1.f + 2.f*xy + wx2*uy2, MIN_NORM));
    float c1 = A*sm*iden, c2 = Bc*iden;
    float z1 = c1*mx + c2*uxi;                     // per-lane vector
    float zz = (A*A*wx2 + 2.f*A*Bc*xy + Bc*Bc*uy2)*iden*iden;   // ||z1||^2
    float zb = (A*sm*mxb + Bc*uxbv)*iden;                       // z1.b
    // h_new = mobius_add(z1, b)
    float A2 = 1.f + 2.f*zb + bn2;
    float B2 = 1.f - zz;
    float iden2 = frcp(fmaxf(1.f + 2.f*zb + zz*bn2, MIN_NORM));
    float hn = (A2*iden2)*z1 + (B2*iden2)*bi;
    encp[(size_t)s*256 + lane] = hn;               // fire-and-forget
    hreg = hn;
    hs[lane] = hn;
    LDS_FENCE();                                   // order broadcast for next matvec
  }
}

// ---- row squared-norms: src is [nrows][64] ----
__global__ __launch_bounds__(256) void k_norm2(const float* __restrict__ src,
    float* __restrict__ dst, int nrows){
  const int row = blockIdx.x*4 + (threadIdx.x>>6);
  const int lane = threadIdx.x & 63;
  if(row >= nrows) return;
  float v = src[(size_t)row*64 + lane];
  float n2 = wred(v*v);
  if(lane==0) dst[row] = n2;
}

// acosh(1+y) = log(1 + y + sqrt(y*(2+y))) — cancellation-free, ~13 VALU ops
// vs libm acoshf's ~350-400 (measured: acoshf was 85% of k_dist's VALU issue).
__device__ __forceinline__ float pdist(float dot, float a, float lb){
  float c2  = fmaxf(a + lb - 2.f*dot, 0.f);
  float iden = frcp(fmaxf((1.f-a)*(1.f-lb), MIN_NORM));
  float y   = fmaxf(2.f*c2*iden, 1e-7f);     // == max(arg,1+1e-7) semantics
  return __logf(1.f + y + fsqrt(y*(2.f+y)));
}

// ---- kernel 3: interaction[b,l,s] = sum_h poinc_dist(enc[b,s,h],lab[l,h]) ----
#define LP 68  // padded LDS stride (64 + 4), keeps b128 16B-aligned, kills conflicts
__global__ __launch_bounds__(256) void k_dist(const float* __restrict__ enc,
    const float* __restrict__ lab, const float* __restrict__ an,
    const float* __restrict__ lbn, float* __restrict__ inter){
  __shared__ __align__(16) float eT[4*16*LP];
  __shared__ __align__(16) float lT[4*16*LP];
  const int bs0 = blockIdx.x*64, l0 = blockIdx.y*64;
  const int t = threadIdx.x;
  const int tr = t>>4, tc = t&15;
  const int ldr = t>>2, ldp = t&3;
  float acc[4][4][4];
#pragma unroll
  for(int h=0;h<4;h++)
#pragma unroll
    for(int i=0;i<4;i++)
#pragma unroll
      for(int j=0;j<4;j++) acc[h][i][j]=0.f;

  for(int c=0;c<4;c++){
    if(c) __syncthreads();
#pragma unroll
    for(int h=0;h<4;h++){
      float4 ev = *(const float4*)&enc[(size_t)(bs0+ldr)*256 + h*64 + c*16 + ldp*4];
      float4 lv = *(const float4*)&lab[(size_t)(l0 +ldr)*256 + h*64 + c*16 + ldp*4];
      int base = (h*16 + ldp*4)*LP + ldr;
      eT[base     ] = ev.x; eT[base+  LP] = ev.y; eT[base+2*LP] = ev.z; eT[base+3*LP] = ev.w;
      lT[base     ] = lv.x; lT[base+  LP] = lv.y; lT[base+2*LP] = lv.z; lT[base+3*LP] = lv.w;
    }
    __syncthreads();
#pragma unroll
    for(int dd=0;dd<16;dd++){
#pragma unroll
      for(int h=0;h<4;h++){
        float4 e4 = *(const float4*)&eT[(h*16+dd)*LP + tr*4];
        float4 l4 = *(const float4*)&lT[(h*16+dd)*LP + tc*4];
        float ee[4] = {e4.x,e4.y,e4.z,e4.w};
        float ll[4] = {l4.x,l4.y,l4.z,l4.w};
#pragma unroll
        for(int i=0;i<4;i++)
#pragma unroll
          for(int j=0;j<4;j++)
            acc[h][i][j] = fmaf(ee[i], ll[j], acc[h][i][j]);
      }
    }
  }
  const int b = bs0 >> 8;
#pragma unroll
  for(int i=0;i<4;i++){
    const int bs = bs0 + tr*4 + i;
    const int s  = bs & 255;
    float4 ah = *(const float4*)&an[(size_t)bs*4];
#pragma unroll
    for(int j=0;j<4;j++){
      const int l = l0 + tc*4 + j;
      float4 lb = *(const float4*)&lbn[(size_t)l*4];
      float d = pdist(acc[0][i][j], ah.x, lb.x)
              + pdist(acc[1][i][j], ah.y, lb.y)
              + pdist(acc[2][i][j], ah.z, lb.z)
              + pdist(acc[3][i][j], ah.w, lb.w);
      inter[((size_t)b*1024 + l)*256 + s] = d;
    }
  }
}

// ---- kernel 4: out[b,l] = w2 . relu(w1 @ inter[b,l,:] + b1) + b2 ----
__global__ __launch_bounds__(256) void k_mlp(const float* __restrict__ inter,
    const float* __restrict__ w1, const float* __restrict__ b1,
    const float* __restrict__ w2, const float* __restrict__ b2,
    float* __restrict__ out){
  __shared__ __align__(16) float rows[32*256];
  __shared__ float part[4][16];
  const int b  = blockIdx.x >> 5;
  const int l0 = (blockIdx.x & 31)*32;
  const int t = threadIdx.x;
  const float* ip = inter + ((size_t)b*1024 + l0)*256;
#pragma unroll
  for(int k=0;k<8;k++){
    int idx = k*1024 + t*4;
    *(float4*)&rows[idx] = *(const float4*)&ip[idx];
  }
  __syncthreads();
  const int f = t & 127, g = t >> 7;
  float acc[16];
#pragma unroll
  for(int li=0;li<16;li++) acc[li]=0.f;
  const float* wp = w1 + (size_t)f*256;
  for(int s=0;s<256;s+=4){
    float4 w4 = *(const float4*)&wp[s];
#pragma unroll
    for(int li=0;li<16;li++){
      float4 r4 = *(const float4*)&rows[(g*16+li)*256 + s];
      acc[li] = fmaf(r4.w, w4.w, fmaf(r4.z, w4.z, fmaf(r4.y, w4.y, fmaf(r4.x, w4.x, acc[li]))));
    }
  }
  const float bb1 = b1[f], ww2 = w2[f];
  const int wave = t>>6, lane = t&63;
#pragma unroll
  for(int li=0;li<16;li++){
    float vv = fmaxf(acc[li] + bb1, 0.f) * ww2;
    vv = wred(vv);
    if(lane==0) part[wave][li] = vv;
  }
  __syncthreads();
  if(t < 32){
    int g2 = t>>4, li = t&15;
    out[(size_t)b*1024 + l0 + g2*16 + li] = part[2*g2][li] + part[2*g2+1][li] + b2[0];
  }
}

extern "C" void kernel_launch(void* const* d_in, const int* in_sizes, int n_in,
                              void* d_out, int out_size, void* d_ws, size_t ws_size,
                              hipStream_t stream){
  const int*   x    = (const int*)d_in[0];
  const float* wemb = (const float*)d_in[1];
  const float* lab  = (const float*)d_in[2];
  const float* W    = (const float*)d_in[3];
  const float* U    = (const float*)d_in[4];
  const float* bv   = (const float*)d_in[5];
  const float* w1   = (const float*)d_in[6];
  const float* b1   = (const float*)d_in[7];
  const float* w2   = (const float*)d_in[8];
  const float* b2   = (const float*)d_in[9];
  float* out = (float*)d_out;

  float* ws    = (float*)d_ws;
  float* enc   = ws;                      // 2,097,152 f  [B*S*H][64]
  float* an    = enc + 2097152;           //    32,768 f  [B*S*H]
  float* lbn   = an  + 32768;             //     4,096 f  [L*H]
  float* ux    = lbn + 4096;              // 2,097,152 f  (dead after k_rnn)
  float* uxn2  = ux  + 2097152;           //    32,768 f
  float* uxb   = uxn2 + 32768;            //    32,768 f
  float* inter = lbn + 4096;              // 8,388,608 f  [B][L][S] (overlaps ux region)
  // peak ws use: 2134016 + 8388608 floats ≈ 42.1 MB

  k_ux   <<<8192, 256, 0, stream>>>(x, wemb, U, bv, ux, uxn2, uxb);
  k_norm2<<<1024, 256, 0, stream>>>(lab, lbn, 4096);
  k_rnn  <<<128,   64, 0, stream>>>(W, bv, ux, uxn2, uxb, enc);
  k_norm2<<<8192, 256, 0, stream>>>(enc, an, 32768);
  dim3 g3(128, 16);
  k_dist <<<g3,   256, 0, stream>>>(enc, lab, an, lbn, inter);
  k_mlp  <<<1024, 256, 0, stream>>>(inter, w1, b1, w2, b2, out);
}